// Round 7
// baseline (362.979 us; speedup 1.0000x reference)
//
#include <hip/hip_runtime.h>
#include <hip/hip_bf16.h>

#define NQ    40000
#define DD    256
#define NHH   8
#define NPP   8
#define DFF   1024
#define BEV   200
#define MPAD  40064   // 313 * 128

typedef __attribute__((ext_vector_type(4))) float f32x4;
typedef __attribute__((ext_vector_type(8))) short s16x8;
typedef __hip_bfloat16 bf16;

#define AS1(p) ((const __attribute__((address_space(1))) void*)(p))
#define AS3(p) ((__attribute__((address_space(3))) void*)(p))

__device__ inline unsigned short f2bf(float f) {
  union { bf16 h; unsigned short u; } cv;
  cv.h = __float2bfloat16(f);
  return cv.u;
}
__device__ inline float bf2f(bf16 h) { return __bfloat162float(h); }
__device__ inline float bfs(short u) {
  union { float f; unsigned u; } c;
  c.u = ((unsigned)(unsigned short)u) << 16;
  return c.f;
}

// ---------------------------------------------------------------- weights
// dst[c*R + r] = src[r*C + c]   (src is [R][C] f32, dst is [C][R] bf16)
__global__ void transpose_cvt(const float* __restrict__ src, bf16* __restrict__ dst,
                              int R, int C) {
  int i = blockIdx.x * 256 + threadIdx.x;
  if (i >= R * C) return;
  int c = i / R, r = i % R;
  dst[i] = __float2bfloat16(src[(size_t)r * C + c]);
}

// Wq_t [256][256] bf16: row n<128: W_off col n; 128..191: W_attn; 192,193: W_ref; rest 0
__global__ void build_wq(const float* __restrict__ Woff, const float* __restrict__ Wattn,
                         const float* __restrict__ Wref, bf16* __restrict__ dst) {
  int i = blockIdx.x * 256 + threadIdx.x;   // 65536
  int n = i >> 8, k = i & 255;
  float v;
  if (n < 128)      v = Woff[k * 128 + n];
  else if (n < 192) v = Wattn[k * 64 + (n - 128)];
  else if (n < 194) v = Wref[k * 2 + (n - 192)];
  else              v = 0.f;
  dst[i] = __float2bfloat16(v);
}

// ---------------------------------------------------------------- GEMM
// C[M][N] = A[Mpad][K] x Bt[N][K]^T  (bf16 MFMA, f32 acc)
// 128x128 tile, BK_ in {32,64}, 256 threads (4 waves 2x2), single-buffer
// staging (round-4 A/B: dbuf cut occupancy, regressed), XCD chunk swizzle
// (round-4/5 A/B: FETCH 81->12 MB on FFN1).
// BK_=32 (16KB LDS): ~2x resident blocks vs BK_=64 -> block-level overlap
// hides stage latency (round-5: latency-bound, MfmaUtil 11%, nothing saturated).
// SRC: 0 = A bf16 via global_load_lds; 1 = A f32 (cvt at stage); 2 = A f32 sum
// of two sources (kills the standalone cvt/addcvt elementwise kernels).
// SRC>0 requires BK_=32 (one reg-stage pass per K-step).
template<int SRC, int BK_, bool RELU>
__global__ void gemm_bt(const bf16* __restrict__ A,
                        const float* __restrict__ Af0, const float* __restrict__ Af1,
                        const bf16* __restrict__ Bt,
                        int K, int Ntiles, int N,
                        const float* __restrict__ bias, float biasScale,
                        const bf16* __restrict__ addB, const float* __restrict__ addF,
                        float addScale,
                        bf16* __restrict__ outB, float* __restrict__ outF, int Mvalid) {
  constexpr int HALF = BK_ * 256;              // bytes per (A or B) half-tile
  constexpr int ROWB = BK_ * 2;                // bytes per tile row
  __shared__ __align__(16) char smem[BK_ * 512];
  const int tid  = threadIdx.x;
  const int wave = tid >> 6, lane = tid & 63;
  // XCD-aware chunked remap (bijective for any nwg)
  const int nwg = gridDim.x;
  const int orig = blockIdx.x;
  const int q8 = nwg >> 3, r8 = nwg & 7;
  const int xcd = orig & 7, idx = orig >> 3;
  const int wg = (xcd < r8 ? xcd * (q8 + 1) : r8 * (q8 + 1) + (xcd - r8) * q8) + idx;
  const int tm = wg / Ntiles, tn = wg % Ntiles;
  const int wr = wave >> 1, wc = wave & 1;

  f32x4 acc[4][4];
#pragma unroll
  for (int i = 0; i < 4; ++i)
#pragma unroll
    for (int j = 0; j < 4; ++j) {
      f32x4 z = {0.f, 0.f, 0.f, 0.f};
      acc[i][j] = z;
    }

  const char* Ab = (const char*)A;
  const char* Bb = (const char*)Bt;
  const int nK = K / BK_;

  for (int kt = 0; kt < nK; ++kt) {
    if constexpr (SRC == 0) {
      constexpr int WI = BK_ / 8;              // wave-instrs per wave (both halves)
#pragma unroll
      for (int i = 0; i < WI; ++i) {
        const int j  = wave * WI + i;
        const int p0 = j << 10;                // 1KB per wave-instruction
        const char* g;
        if (p0 < HALF) {                       // A half: [128][BK_] bf16
          const int pl = p0 + lane * 16;
          const int row = pl / ROWB, cb = pl % ROWB;
          g = Ab + ((size_t)(tm * 128 + row) * K + kt * BK_) * 2 + cb;
        } else {                               // B half: [128][BK_] bf16 (rows = C-cols)
          const int pl = p0 - HALF + lane * 16;
          const int row = pl / ROWB, cb = pl % ROWB;
          g = Bb + ((size_t)(tn * 128 + row) * K + kt * BK_) * 2 + cb;
        }
        __builtin_amdgcn_global_load_lds(AS1(g), AS3(smem + p0), 16, 0, 0);
      }
    } else {
      // A half reg-staged from f32 (BK_=32): thread -> 16 elems of [128][32]
      const int row = tid >> 1, c0 = (tid & 1) * 16;
      const int srow = min(tm * 128 + row, Mvalid - 1);   // inputs have Mvalid rows only
      const float* s0 = Af0 + (size_t)srow * K + kt * 32 + c0;
      float4 f[4];
#pragma unroll
      for (int i = 0; i < 4; ++i) f[i] = ((const float4*)s0)[i];
      if constexpr (SRC == 2) {
        const float* s1 = Af1 + (size_t)srow * K + kt * 32 + c0;
#pragma unroll
        for (int i = 0; i < 4; ++i) {
          float4 g4 = ((const float4*)s1)[i];
          f[i].x += g4.x; f[i].y += g4.y; f[i].z += g4.z; f[i].w += g4.w;
        }
      }
      s16x8 w0, w1;
#pragma unroll
      for (int i = 0; i < 2; ++i) {
        w0[i * 4 + 0] = (short)f2bf(f[i].x);     w0[i * 4 + 1] = (short)f2bf(f[i].y);
        w0[i * 4 + 2] = (short)f2bf(f[i].z);     w0[i * 4 + 3] = (short)f2bf(f[i].w);
        w1[i * 4 + 0] = (short)f2bf(f[i + 2].x); w1[i * 4 + 1] = (short)f2bf(f[i + 2].y);
        w1[i * 4 + 2] = (short)f2bf(f[i + 2].z); w1[i * 4 + 3] = (short)f2bf(f[i + 2].w);
      }
      *(s16x8*)(smem + row * 64 + c0 * 2)      = w0;
      *(s16x8*)(smem + row * 64 + c0 * 2 + 16) = w1;
      // B half via global_load_lds: 8KB, 2 wave-instrs per wave
#pragma unroll
      for (int i = 0; i < 2; ++i) {
        const int p0 = (wave * 2 + i) << 10;
        const int pl = p0 + lane * 16;
        const int rowB = pl >> 6, cb = pl & 63;
        const char* g = Bb + ((size_t)(tn * 128 + rowB) * K + kt * 32) * 2 + cb;
        __builtin_amdgcn_global_load_lds(AS1(g), AS3(smem + HALF + p0), 16, 0, 0);
      }
    }
    __syncthreads();

    constexpr int NKK = BK_ / 32;
#pragma unroll
    for (int kk = 0; kk < NKK; ++kk) {
      const int r  = lane & 15;
      const int kb = kk * 64 + (lane >> 4) * 16;   // byte offset of k-chunk
      s16x8 af[4], bfr[4];
#pragma unroll
      for (int mr = 0; mr < 4; ++mr)
        af[mr] = *(const s16x8*)(smem + (wr * 64 + mr * 16 + r) * ROWB + kb);
#pragma unroll
      for (int nr = 0; nr < 4; ++nr)
        bfr[nr] = *(const s16x8*)(smem + HALF + (wc * 64 + nr * 16 + r) * ROWB + kb);
#pragma unroll
      for (int mr = 0; mr < 4; ++mr)
#pragma unroll
        for (int nr = 0; nr < 4; ++nr)
          acc[mr][nr] = __builtin_amdgcn_mfma_f32_16x16x32_bf16(af[mr], bfr[nr], acc[mr][nr], 0, 0, 0);
    }
    __syncthreads();
  }

  // epilogue: C/D frag mapping col = lane&15, row = (lane>>4)*4 + j
  const int r = lane & 15, rg = lane >> 4;
#pragma unroll
  for (int mr = 0; mr < 4; ++mr) {
#pragma unroll
    for (int nr = 0; nr < 4; ++nr) {
      const int gn = tn * 128 + wc * 64 + nr * 16 + r;
      const float bval = bias ? biasScale * bias[gn] : 0.f;
#pragma unroll
      for (int j2 = 0; j2 < 4; ++j2) {
        const int gm = tm * 128 + wr * 64 + mr * 16 + rg * 4 + j2;
        float v = acc[mr][nr][j2] + bval;
        if (gm < Mvalid) {
          if (addB) v += addScale * bf2f(addB[(size_t)gm * N + gn]);
          else if (addF) v += addScale * addF[(size_t)gm * N + gn];
        }
        if (RELU) v = fmaxf(v, 0.f);
        if (outB) outB[(size_t)gm * N + gn] = __float2bfloat16(v);
        if (outF && gm < Mvalid) outF[(size_t)gm * N + gn] = v;
      }
    }
  }
}

// ---------------------------------------------------------------- samp finalize
// raw[q][0..127]=off logits, [128..191]=attn logits, [192..193]=ref logits (no bias yet)
// -> samp[q][hp] = (px, py, attn_weight)
__global__ void finalize_kernel(const bf16* __restrict__ raw, const float* __restrict__ b_off,
                                const float* __restrict__ b_attn, const float* __restrict__ b_ref,
                                float* __restrict__ samp) {
  __shared__ float r[4][256];
  const int tid = threadIdx.x;
  const int q0 = blockIdx.x * 4;
#pragma unroll
  for (int i = 0; i < 4; ++i) {
    int e = tid + i * 256;
    int ql = e >> 8, k = e & 255;
    r[ql][k] = bf2f(raw[(size_t)(q0 + ql) * 256 + k]);
  }
  __syncthreads();
  const int ql = tid >> 6, hp = tid & 63;
  const int h = hp >> 3, p = hp & 7;
  float v[8];
  float m = -1e30f;
#pragma unroll
  for (int pp = 0; pp < 8; ++pp) {
    v[pp] = r[ql][128 + h * 8 + pp] + b_attn[h * 8 + pp];
    m = fmaxf(m, v[pp]);
  }
  float s = 0.f;
#pragma unroll
  for (int pp = 0; pp < 8; ++pp) { v[pp] = expf(v[pp] - m); s += v[pp]; }
  const float w = v[p] / s;
  const float sx = 1.f / (1.f + expf(-(r[ql][192] + b_ref[0])));
  const float sy = 1.f / (1.f + expf(-(r[ql][193] + b_ref[1])));
  // px = loc_x*BEV_W - 0.5 = sigmoid(ref_x)*W + off_x - 0.5   (off normalizer = W)
  const float px = sx * (float)BEV + (r[ql][hp * 2 + 0] + b_off[hp * 2 + 0]) - 0.5f;
  const float py = sy * (float)BEV + (r[ql][hp * 2 + 1] + b_off[hp * 2 + 1]) - 0.5f;
  const size_t o = ((size_t)(q0 + ql) * 64 + hp) * 3;
  samp[o] = px; samp[o + 1] = py; samp[o + 2] = w;
}

// ---------------------------------------------------------------- deform gather
// 8 queries per block; 32 threads per query: thread = (head, dword-group).
// Each thread accumulates 8 channels with 16B s16x8 loads per corner.
// Zero-padding via clamped index + zeroed weight (branch-free).
// unroll 2 (not 8): caps in-flight load payload at ~32 VGPR -> no scratch
// spills (round-2 showed 177MB hidden spill writes at full unroll).
__global__ __launch_bounds__(256, 4)
void deform_kernel(const float* __restrict__ samp, const bf16* __restrict__ val,
                   bf16* __restrict__ out) {
  __shared__ float s[8 * 192];
  const int tid = threadIdx.x;
  const int q0 = blockIdx.x * 8;
#pragma unroll
  for (int i = 0; i < 6; ++i) {
    const int e = tid + i * 256;
    s[e] = samp[(size_t)q0 * 192 + e];
  }
  __syncthreads();
  const int ql = tid >> 5;          // 0..7 query within block
  const int lane5 = tid & 31;
  const int h = lane5 >> 2;         // 0..7 head
  const int dg = lane5 & 3;         // 0..3 dword-group (8 channels)
  const float* sp = s + ql * 192 + h * 24;
  const bf16* vb = val + h * 32 + dg * 8;

  float acc[8] = {0.f, 0.f, 0.f, 0.f, 0.f, 0.f, 0.f, 0.f};
#pragma unroll 2
  for (int p = 0; p < 8; ++p) {
    const float px = sp[p * 3 + 0], py = sp[p * 3 + 1], w = sp[p * 3 + 2];
    const float xf = floorf(px), yf = floorf(py);
    const int x0 = (int)xf, y0 = (int)yf;
    const float lx = px - xf, ly = py - yf;
    const float xa = (x0 >= 0 && x0 < BEV) ? 1.f : 0.f;
    const float xb = (x0 + 1 >= 0 && x0 + 1 < BEV) ? 1.f : 0.f;
    const float ya = (y0 >= 0 && y0 < BEV) ? 1.f : 0.f;
    const float yb = (y0 + 1 >= 0 && y0 + 1 < BEV) ? 1.f : 0.f;
    const float w00 = w * (1.f - lx) * (1.f - ly) * xa * ya;
    const float w10 = w * lx * (1.f - ly) * xb * ya;
    const float w01 = w * (1.f - lx) * ly * xa * yb;
    const float w11 = w * lx * ly * xb * yb;
    const int cx0 = min(max(x0, 0), BEV - 1);
    const int cx1 = min(max(x0 + 1, 0), BEV - 1);
    const int cy0 = min(max(y0, 0), BEV - 1) * BEV;
    const int cy1 = min(max(y0 + 1, 0), BEV - 1) * BEV;
    const s16x8 v00 = *(const s16x8*)(vb + (size_t)(cy0 + cx0) * 256);
    const s16x8 v10 = *(const s16x8*)(vb + (size_t)(cy0 + cx1) * 256);
    const s16x8 v01 = *(const s16x8*)(vb + (size_t)(cy1 + cx0) * 256);
    const s16x8 v11 = *(const s16x8*)(vb + (size_t)(cy1 + cx1) * 256);
#pragma unroll
    for (int j = 0; j < 8; ++j) {
      acc[j] += w00 * bfs(v00[j]) + w10 * bfs(v10[j])
              + w01 * bfs(v01[j]) + w11 * bfs(v11[j]);
    }
  }
  s16x8 o;
#pragma unroll
  for (int j = 0; j < 8; ++j) o[j] = (short)f2bf(acc[j]);
  *(s16x8*)(out + (size_t)(q0 + ql) * 256 + h * 32 + dg * 8) = o;
}

// ---------------------------------------------------------------- host
extern "C" void kernel_launch(void* const* d_in, const int* in_sizes, int n_in,
                              void* d_out, int out_size, void* d_ws, size_t ws_size,
                              hipStream_t stream) {
  const float* B0     = (const float*)d_in[0];
  const float* B1     = (const float*)d_in[1];
  const float* qe     = (const float*)d_in[2];
  const float* W_ref  = (const float*)d_in[3];
  const float* b_ref  = (const float*)d_in[4];
  const float* W_off  = (const float*)d_in[5];
  const float* b_off  = (const float*)d_in[6];
  const float* W_attn = (const float*)d_in[7];
  const float* b_attn = (const float*)d_in[8];
  const float* W_val  = (const float*)d_in[9];
  const float* b_val  = (const float*)d_in[10];
  const float* W_out  = (const float*)d_in[11];
  const float* b_out  = (const float*)d_in[12];
  const float* W_ffn1 = (const float*)d_in[13];
  const float* b_ffn1 = (const float*)d_in[14];
  const float* W_ffn2 = (const float*)d_in[15];
  const float* b_ffn2 = (const float*)d_in[16];
  float* out = (float*)d_out;
  char* ws = (char*)d_ws;

  // workspace layout (bytes)
  const size_t SZ_MAT = (size_t)MPAD * 256 * 2;        // 20,512,768
  const size_t VAL_OFF    = 0;                          // val bf16
  const size_t RAW_OFF    = SZ_MAT;                     // raw / deform (aliased, serialized)
  const size_t BSH_OFF    = 2 * SZ_MAT;                 // Bshort bf16
  const size_t H_OFF      = 3 * SZ_MAT;                 // H [MPAD][1024] bf16 (82MB)
  const size_t H_BYTES    = (size_t)MPAD * 1024 * 2;
  const size_t SAMP_OFF   = H_OFF + H_BYTES;            // samp f32 [NQ][64][3]
  const size_t SAMP_BYTES = (size_t)NQ * 192 * 4;
  const size_t WQ_OFF     = SAMP_OFF + SAMP_BYTES;
  const size_t WVAL_OFF   = WQ_OFF   + 256 * 256 * 2;
  const size_t WOUT_OFF   = WVAL_OFF + 256 * 256 * 2;
  const size_t WF1_OFF    = WOUT_OFF + 256 * 256 * 2;
  const size_t WF2_OFF    = WF1_OFF  + 1024 * 256 * 2;

  bf16* valb  = (bf16*)(ws + VAL_OFF);
  bf16* rawb  = (bf16*)(ws + RAW_OFF);
  bf16* defb  = rawb;                    // aliased (raw dead after finalize)
  bf16* bshb  = (bf16*)(ws + BSH_OFF);
  bf16* hbuf  = (bf16*)(ws + H_OFF);
  float* samp = (float*)(ws + SAMP_OFF);
  bf16* wq    = (bf16*)(ws + WQ_OFF);
  bf16* wval  = (bf16*)(ws + WVAL_OFF);
  bf16* wout  = (bf16*)(ws + WOUT_OFF);
  bf16* wf1   = (bf16*)(ws + WF1_OFF);
  bf16* wf2   = (bf16*)(ws + WF2_OFF);

  const int MT = MPAD / 128;             // 313

  // weights -> transposed bf16
  build_wq<<<256, 256, 0, stream>>>(W_off, W_attn, W_ref, wq);
  transpose_cvt<<<(256 * 256 + 255) / 256, 256, 0, stream>>>(W_val, wval, 256, 256);
  transpose_cvt<<<(256 * 256 + 255) / 256, 256, 0, stream>>>(W_out, wout, 256, 256);
  transpose_cvt<<<(256 * 1024 + 255) / 256, 256, 0, stream>>>(W_ffn1, wf1, 256, 1024);
  transpose_cvt<<<(1024 * 256 + 255) / 256, 256, 0, stream>>>(W_ffn2, wf2, 1024, 256);

  // raw logits = q @ Wq^T  (A from qe f32, cvt at stage)
  gemm_bt<1, 32, false><<<MT * 2, 256, 0, stream>>>(
      nullptr, qe, nullptr, wq, 256, 2, 256,
      nullptr, 0.f, nullptr, nullptr, 0.f, rawb, nullptr, NQ);
  finalize_kernel<<<NQ / 4, 256, 0, stream>>>(rawb, b_off, b_attn, b_ref, samp);

  // val = (B0+B1) @ W_val + 2*b_val  (A = B0+B1 summed at stage)
  gemm_bt<2, 32, false><<<MT * 2, 256, 0, stream>>>(
      nullptr, B0, B1, wval, 256, 2, 256,
      b_val, 2.f, nullptr, nullptr, 0.f, valb, nullptr, NQ);

  deform_kernel<<<NQ / 8, 256, 0, stream>>>(samp, valb, defb);

  // B_short = deform @ W_out + 2*b_out + 2*q  (residual from qe f32 in epilogue)
  gemm_bt<0, 32, false><<<MT * 2, 256, 0, stream>>>(
      defb, nullptr, nullptr, wout, 256, 2, 256,
      b_out, 2.f, nullptr, qe, 2.f, bshb, nullptr, NQ);

  // H = relu(B_short @ W_ffn1 + b_ffn1)
  gemm_bt<0, 32, true><<<MT * 8, 256, 0, stream>>>(
      bshb, nullptr, nullptr, wf1, 256, 8, 1024,
      b_ffn1, 1.f, nullptr, nullptr, 0.f, hbuf, nullptr, NQ);

  // out = B_short + H @ W_ffn2 + b_ffn2   (BK=64 control; sole f32 writer of d_out)
  gemm_bt<0, 64, false><<<MT * 2, 256, 0, stream>>>(
      hbuf, nullptr, nullptr, wf2, 1024, 2, 256,
      b_ffn2, 1.f, bshb, nullptr, 1.f, nullptr, out, NQ);
}

// Round 8
// 265.159 us; speedup vs baseline: 1.3689x; 1.3689x over previous
//
#include <hip/hip_runtime.h>
#include <hip/hip_bf16.h>

#define NQ    40000
#define DD    256
#define NHH   8
#define NPP   8
#define DFF   1024
#define BEV   200
#define MPAD  40064   // 313 * 128

typedef __attribute__((ext_vector_type(4))) float f32x4;
typedef __attribute__((ext_vector_type(8))) short s16x8;
typedef __hip_bfloat16 bf16;

#define AS1(p) ((const __attribute__((address_space(1))) void*)(p))
#define AS3(p) ((__attribute__((address_space(3))) void*)(p))

__device__ inline unsigned short f2bf(float f) {
  union { bf16 h; unsigned short u; } cv;
  cv.h = __float2bfloat16(f);
  return cv.u;
}
__device__ inline float bf2f(bf16 h) { return __bfloat162float(h); }
__device__ inline float bfs(short u) {
  union { float f; unsigned u; } c;
  c.u = ((unsigned)(unsigned short)u) << 16;
  return c.f;
}

// ---------------------------------------------------------------- weights
// dst[c*R + r] = src[r*C + c]   (src is [R][C] f32, dst is [C][R] bf16)
__global__ void transpose_cvt(const float* __restrict__ src, bf16* __restrict__ dst,
                              int R, int C) {
  int i = blockIdx.x * 256 + threadIdx.x;
  if (i >= R * C) return;
  int c = i / R, r = i % R;
  dst[i] = __float2bfloat16(src[(size_t)r * C + c]);
}

// Wq_t [256][256] bf16: row n<128: W_off col n; 128..191: W_attn; 192,193: W_ref; rest 0
__global__ void build_wq(const float* __restrict__ Woff, const float* __restrict__ Wattn,
                         const float* __restrict__ Wref, bf16* __restrict__ dst) {
  int i = blockIdx.x * 256 + threadIdx.x;   // 65536
  int n = i >> 8, k = i & 255;
  float v;
  if (n < 128)      v = Woff[k * 128 + n];
  else if (n < 192) v = Wattn[k * 64 + (n - 128)];
  else if (n < 194) v = Wref[k * 2 + (n - 192)];
  else              v = 0.f;
  dst[i] = __float2bfloat16(v);
}

// ---------------------------------------------------------------- elementwise cvt
__global__ void cvt_bf16_kernel(const float* __restrict__ src, bf16* __restrict__ dst, int n4) {
  int i = blockIdx.x * 256 + threadIdx.x;
  if (i >= n4) return;
  float4 v = ((const float4*)src)[i];
  ushort4 o;
  o.x = f2bf(v.x); o.y = f2bf(v.y); o.z = f2bf(v.z); o.w = f2bf(v.w);
  ((ushort4*)dst)[i] = o;
}

__global__ void addcvt_kernel(const float* __restrict__ a, const float* __restrict__ b,
                              bf16* __restrict__ dst, int n4) {
  int i = blockIdx.x * 256 + threadIdx.x;
  if (i >= n4) return;
  float4 va = ((const float4*)a)[i];
  float4 vb = ((const float4*)b)[i];
  ushort4 o;
  o.x = f2bf(va.x + vb.x); o.y = f2bf(va.y + vb.y);
  o.z = f2bf(va.z + vb.z); o.w = f2bf(va.w + vb.w);
  ((ushort4*)dst)[i] = o;
}

// ---------------------------------------------------------------- GEMM
// C[M][N] = A[Mpad][K](bf16) x Bt[N][K](bf16)^T, 128x128 tile, 4 waves 2x2.
// BK_=32, DOUBLE-buffered at 32KB total LDS (== round-5's single-buffer
// footprint, so residency is preserved; round-4's dbuf regression came from
// 64KB + launch_bounds cap, round-7 showed LDS was not the occupancy limiter).
// Issue-early: stage(kt+1) BEFORE compute(kt), ONE barrier per K-step --
// load latency overlaps current step's ds_read+MFMA (T3-minimum 2-phase).
// XCD chunk swizzle (round-4/5 A/B: FFN1 FETCH 81->12 MB).
template<int BK_, bool RELU>
__global__ void gemm_bt(const bf16* __restrict__ A, const bf16* __restrict__ Bt,
                        int K, int Ntiles, int N,
                        const float* __restrict__ bias, float biasScale,
                        const bf16* __restrict__ addB, float addScale,
                        bf16* __restrict__ outB, float* __restrict__ outF, int Mvalid) {
  constexpr int HALF = BK_ * 256;              // bytes per (A or B) half-tile
  constexpr int ROWB = BK_ * 2;                // bytes per tile row
  constexpr int BUFB = BK_ * 512;              // bytes per buffer (A+B)
  __shared__ __align__(16) char smem[2 * BUFB];
  const int tid  = threadIdx.x;
  const int wave = tid >> 6, lane = tid & 63;
  // XCD-aware chunked remap (bijective for any nwg)
  const int nwg = gridDim.x;
  const int orig = blockIdx.x;
  const int q8 = nwg >> 3, r8 = nwg & 7;
  const int xcd = orig & 7, idx = orig >> 3;
  const int wg = (xcd < r8 ? xcd * (q8 + 1) : r8 * (q8 + 1) + (xcd - r8) * q8) + idx;
  const int tm = wg / Ntiles, tn = wg % Ntiles;
  const int wr = wave >> 1, wc = wave & 1;

  f32x4 acc[4][4];
#pragma unroll
  for (int i = 0; i < 4; ++i)
#pragma unroll
    for (int j = 0; j < 4; ++j) {
      f32x4 z = {0.f, 0.f, 0.f, 0.f};
      acc[i][j] = z;
    }

  const char* Ab = (const char*)A;
  const char* Bb = (const char*)Bt;
  const int nK = K / BK_;

  auto stage = [&](int bufBase, int kt) {
    constexpr int WI = BK_ / 8;                // wave-instrs per wave
#pragma unroll
    for (int i = 0; i < WI; ++i) {
      const int j  = wave * WI + i;
      const int p0 = j << 10;                  // 1KB per wave-instruction
      const char* g;
      if (p0 < HALF) {                         // A half: [128][BK_] bf16
        const int pl = p0 + lane * 16;
        const int row = pl / ROWB, cb = pl % ROWB;
        g = Ab + ((size_t)(tm * 128 + row) * K + kt * BK_) * 2 + cb;
      } else {                                 // B half: [128][BK_] bf16 (rows = C-cols)
        const int pl = p0 - HALF + lane * 16;
        const int row = pl / ROWB, cb = pl % ROWB;
        g = Bb + ((size_t)(tn * 128 + row) * K + kt * BK_) * 2 + cb;
      }
      __builtin_amdgcn_global_load_lds(AS1(g), AS3(smem + bufBase + p0), 16, 0, 0);
    }
  };

  stage(0, 0);
  __syncthreads();
  int cur = 0;
  for (int kt = 0; kt < nK; ++kt) {
    if (kt + 1 < nK) stage((cur ^ 1) * BUFB, kt + 1);   // issue-early prefetch
    const char* sbuf = smem + cur * BUFB;
    constexpr int NKK = BK_ / 32;
#pragma unroll
    for (int kk = 0; kk < NKK; ++kk) {
      const int r  = lane & 15;
      const int kb = kk * 64 + (lane >> 4) * 16;   // byte offset of k-chunk
      s16x8 af[4], bfr[4];
#pragma unroll
      for (int mr = 0; mr < 4; ++mr)
        af[mr] = *(const s16x8*)(sbuf + (wr * 64 + mr * 16 + r) * ROWB + kb);
#pragma unroll
      for (int nr = 0; nr < 4; ++nr)
        bfr[nr] = *(const s16x8*)(sbuf + HALF + (wc * 64 + nr * 16 + r) * ROWB + kb);
#pragma unroll
      for (int mr = 0; mr < 4; ++mr)
#pragma unroll
        for (int nr = 0; nr < 4; ++nr)
          acc[mr][nr] = __builtin_amdgcn_mfma_f32_16x16x32_bf16(af[mr], bfr[nr], acc[mr][nr], 0, 0, 0);
    }
    __syncthreads();   // drains prefetch loads (overlapped with MFMA above)
    cur ^= 1;
  }

  // epilogue: C/D frag mapping col = lane&15, row = (lane>>4)*4 + j
  const int r = lane & 15, rg = lane >> 4;
#pragma unroll
  for (int mr = 0; mr < 4; ++mr) {
#pragma unroll
    for (int nr = 0; nr < 4; ++nr) {
      const int gn = tn * 128 + wc * 64 + nr * 16 + r;
      const float bval = bias ? biasScale * bias[gn] : 0.f;
#pragma unroll
      for (int j2 = 0; j2 < 4; ++j2) {
        const int gm = tm * 128 + wr * 64 + mr * 16 + rg * 4 + j2;
        float v = acc[mr][nr][j2] + bval;
        if (addB && gm < Mvalid) v += addScale * bf2f(addB[(size_t)gm * N + gn]);
        if (RELU) v = fmaxf(v, 0.f);
        if (outB) outB[(size_t)gm * N + gn] = __float2bfloat16(v);
        if (outF && gm < Mvalid) outF[(size_t)gm * N + gn] = v;
      }
    }
  }
}

// ---------------------------------------------------------------- samp finalize
// raw[q][0..127]=off logits, [128..191]=attn logits, [192..193]=ref logits (no bias yet)
// -> samp[q][hp] = (px, py, attn_weight)
__global__ void finalize_kernel(const bf16* __restrict__ raw, const float* __restrict__ b_off,
                                const float* __restrict__ b_attn, const float* __restrict__ b_ref,
                                float* __restrict__ samp) {
  __shared__ float r[4][256];
  const int tid = threadIdx.x;
  const int q0 = blockIdx.x * 4;
#pragma unroll
  for (int i = 0; i < 4; ++i) {
    int e = tid + i * 256;
    int ql = e >> 8, k = e & 255;
    r[ql][k] = bf2f(raw[(size_t)(q0 + ql) * 256 + k]);
  }
  __syncthreads();
  const int ql = tid >> 6, hp = tid & 63;
  const int h = hp >> 3, p = hp & 7;
  float v[8];
  float m = -1e30f;
#pragma unroll
  for (int pp = 0; pp < 8; ++pp) {
    v[pp] = r[ql][128 + h * 8 + pp] + b_attn[h * 8 + pp];
    m = fmaxf(m, v[pp]);
  }
  float s = 0.f;
#pragma unroll
  for (int pp = 0; pp < 8; ++pp) { v[pp] = expf(v[pp] - m); s += v[pp]; }
  const float w = v[p] / s;
  const float sx = 1.f / (1.f + expf(-(r[ql][192] + b_ref[0])));
  const float sy = 1.f / (1.f + expf(-(r[ql][193] + b_ref[1])));
  // px = loc_x*BEV_W - 0.5 = sigmoid(ref_x)*W + off_x - 0.5   (off normalizer = W)
  const float px = sx * (float)BEV + (r[ql][hp * 2 + 0] + b_off[hp * 2 + 0]) - 0.5f;
  const float py = sy * (float)BEV + (r[ql][hp * 2 + 1] + b_off[hp * 2 + 1]) - 0.5f;
  const size_t o = ((size_t)(q0 + ql) * 64 + hp) * 3;
  samp[o] = px; samp[o + 1] = py; samp[o + 2] = w;
}

// ---------------------------------------------------------------- deform gather
// 8 queries per block; 32 threads per query: thread = (head, dword-group).
// Each thread accumulates 8 channels with 16B s16x8 loads per corner.
// Zero-padding via clamped index + zeroed weight (branch-free).
// unroll 2 (not 8): caps in-flight load payload at ~32 VGPR -> no scratch
// spills (round-2 showed 177MB hidden spill writes at full unroll).
__global__ __launch_bounds__(256, 4)
void deform_kernel(const float* __restrict__ samp, const bf16* __restrict__ val,
                   bf16* __restrict__ out) {
  __shared__ float s[8 * 192];
  const int tid = threadIdx.x;
  const int q0 = blockIdx.x * 8;
#pragma unroll
  for (int i = 0; i < 6; ++i) {
    const int e = tid + i * 256;
    s[e] = samp[(size_t)q0 * 192 + e];
  }
  __syncthreads();
  const int ql = tid >> 5;          // 0..7 query within block
  const int lane5 = tid & 31;
  const int h = lane5 >> 2;         // 0..7 head
  const int dg = lane5 & 3;         // 0..3 dword-group (8 channels)
  const float* sp = s + ql * 192 + h * 24;
  const bf16* vb = val + h * 32 + dg * 8;

  float acc[8] = {0.f, 0.f, 0.f, 0.f, 0.f, 0.f, 0.f, 0.f};
#pragma unroll 2
  for (int p = 0; p < 8; ++p) {
    const float px = sp[p * 3 + 0], py = sp[p * 3 + 1], w = sp[p * 3 + 2];
    const float xf = floorf(px), yf = floorf(py);
    const int x0 = (int)xf, y0 = (int)yf;
    const float lx = px - xf, ly = py - yf;
    const float xa = (x0 >= 0 && x0 < BEV) ? 1.f : 0.f;
    const float xb = (x0 + 1 >= 0 && x0 + 1 < BEV) ? 1.f : 0.f;
    const float ya = (y0 >= 0 && y0 < BEV) ? 1.f : 0.f;
    const float yb = (y0 + 1 >= 0 && y0 + 1 < BEV) ? 1.f : 0.f;
    const float w00 = w * (1.f - lx) * (1.f - ly) * xa * ya;
    const float w10 = w * lx * (1.f - ly) * xb * ya;
    const float w01 = w * (1.f - lx) * ly * xa * yb;
    const float w11 = w * lx * ly * xb * yb;
    const int cx0 = min(max(x0, 0), BEV - 1);
    const int cx1 = min(max(x0 + 1, 0), BEV - 1);
    const int cy0 = min(max(y0, 0), BEV - 1) * BEV;
    const int cy1 = min(max(y0 + 1, 0), BEV - 1) * BEV;
    const s16x8 v00 = *(const s16x8*)(vb + (size_t)(cy0 + cx0) * 256);
    const s16x8 v10 = *(const s16x8*)(vb + (size_t)(cy0 + cx1) * 256);
    const s16x8 v01 = *(const s16x8*)(vb + (size_t)(cy1 + cx0) * 256);
    const s16x8 v11 = *(const s16x8*)(vb + (size_t)(cy1 + cx1) * 256);
#pragma unroll
    for (int j = 0; j < 8; ++j) {
      acc[j] += w00 * bfs(v00[j]) + w10 * bfs(v10[j])
              + w01 * bfs(v01[j]) + w11 * bfs(v11[j]);
    }
  }
  s16x8 o;
#pragma unroll
  for (int j = 0; j < 8; ++j) o[j] = (short)f2bf(acc[j]);
  *(s16x8*)(out + (size_t)(q0 + ql) * 256 + h * 32 + dg * 8) = o;
}

// ---------------------------------------------------------------- host
extern "C" void kernel_launch(void* const* d_in, const int* in_sizes, int n_in,
                              void* d_out, int out_size, void* d_ws, size_t ws_size,
                              hipStream_t stream) {
  const float* B0     = (const float*)d_in[0];
  const float* B1     = (const float*)d_in[1];
  const float* qe     = (const float*)d_in[2];
  const float* W_ref  = (const float*)d_in[3];
  const float* b_ref  = (const float*)d_in[4];
  const float* W_off  = (const float*)d_in[5];
  const float* b_off  = (const float*)d_in[6];
  const float* W_attn = (const float*)d_in[7];
  const float* b_attn = (const float*)d_in[8];
  const float* W_val  = (const float*)d_in[9];
  const float* b_val  = (const float*)d_in[10];
  const float* W_out  = (const float*)d_in[11];
  const float* b_out  = (const float*)d_in[12];
  const float* W_ffn1 = (const float*)d_in[13];
  const float* b_ffn1 = (const float*)d_in[14];
  const float* W_ffn2 = (const float*)d_in[15];
  const float* b_ffn2 = (const float*)d_in[16];
  float* out = (float*)d_out;
  char* ws = (char*)d_ws;

  // workspace layout (bytes)
  const size_t SZ_MAT = (size_t)MPAD * 256 * 2;        // 20,512,768
  const size_t VAL_OFF    = 0;                          // val bf16
  const size_t RAW_OFF    = SZ_MAT;                     // raw / deform (aliased, serialized)
  const size_t BSH_OFF    = 2 * SZ_MAT;                 // Bshort bf16
  const size_t H_OFF      = 3 * SZ_MAT;                 // H [MPAD][1024] bf16 (82MB)
  const size_t QE_OFF     = H_OFF;                      // qe bf16 (aliased into H, used early)
  const size_t VSUM_OFF   = H_OFF + SZ_MAT;             // vsum bf16 (aliased into H)
  const size_t H_BYTES    = (size_t)MPAD * 1024 * 2;
  const size_t SAMP_OFF   = H_OFF + H_BYTES;            // samp f32 [NQ][64][3]
  const size_t SAMP_BYTES = (size_t)NQ * 192 * 4;
  const size_t WQ_OFF     = SAMP_OFF + SAMP_BYTES;
  const size_t WVAL_OFF   = WQ_OFF   + 256 * 256 * 2;
  const size_t WOUT_OFF   = WVAL_OFF + 256 * 256 * 2;
  const size_t WF1_OFF    = WOUT_OFF + 256 * 256 * 2;
  const size_t WF2_OFF    = WF1_OFF  + 1024 * 256 * 2;

  bf16* valb  = (bf16*)(ws + VAL_OFF);
  bf16* rawb  = (bf16*)(ws + RAW_OFF);
  bf16* defb  = rawb;                    // aliased (raw dead after finalize)
  bf16* bshb  = (bf16*)(ws + BSH_OFF);
  bf16* hbuf  = (bf16*)(ws + H_OFF);
  bf16* qeb   = (bf16*)(ws + QE_OFF);
  bf16* vsum  = (bf16*)(ws + VSUM_OFF);
  float* samp = (float*)(ws + SAMP_OFF);
  bf16* wq    = (bf16*)(ws + WQ_OFF);
  bf16* wval  = (bf16*)(ws + WVAL_OFF);
  bf16* wout  = (bf16*)(ws + WOUT_OFF);
  bf16* wf1   = (bf16*)(ws + WF1_OFF);
  bf16* wf2   = (bf16*)(ws + WF2_OFF);

  const int n4 = NQ * 256 / 4;           // 2,560,000
  const int MT = MPAD / 128;             // 313

  // weights -> transposed bf16
  build_wq<<<256, 256, 0, stream>>>(W_off, W_attn, W_ref, wq);
  transpose_cvt<<<(256 * 256 + 255) / 256, 256, 0, stream>>>(W_val, wval, 256, 256);
  transpose_cvt<<<(256 * 256 + 255) / 256, 256, 0, stream>>>(W_out, wout, 256, 256);
  transpose_cvt<<<(256 * 1024 + 255) / 256, 256, 0, stream>>>(W_ffn1, wf1, 256, 1024);
  transpose_cvt<<<(1024 * 256 + 255) / 256, 256, 0, stream>>>(W_ffn2, wf2, 1024, 256);

  // activations -> bf16
  cvt_bf16_kernel<<<n4 / 256, 256, 0, stream>>>(qe, qeb, n4);
  addcvt_kernel<<<n4 / 256, 256, 0, stream>>>(B0, B1, vsum, n4);

  // raw logits = q @ Wq^T
  gemm_bt<32, false><<<MT * 2, 256, 0, stream>>>(qeb, wq, 256, 2, 256,
                                                 nullptr, 0.f, nullptr, 0.f,
                                                 rawb, nullptr, NQ);
  finalize_kernel<<<NQ / 4, 256, 0, stream>>>(rawb, b_off, b_attn, b_ref, samp);

  // val = (B0+B1) @ W_val + 2*b_val
  gemm_bt<32, false><<<MT * 2, 256, 0, stream>>>(vsum, wval, 256, 2, 256,
                                                 b_val, 2.f, nullptr, 0.f,
                                                 valb, nullptr, NQ);

  deform_kernel<<<NQ / 8, 256, 0, stream>>>(samp, valb, defb);

  // B_short = deform @ W_out + 2*b_out + 2*q   (bf16 residual)
  gemm_bt<32, false><<<MT * 2, 256, 0, stream>>>(defb, wout, 256, 2, 256,
                                                 b_out, 2.f, qeb, 2.f,
                                                 bshb, nullptr, NQ);

  // H = relu(B_short @ W_ffn1 + b_ffn1)
  gemm_bt<32, true><<<MT * 8, 256, 0, stream>>>(bshb, wf1, 256, 8, 1024,
                                                b_ffn1, 1.f, nullptr, 0.f,
                                                hbuf, nullptr, NQ);

  // out = B_short + H @ W_ffn2 + b_ffn2   (sole f32 writer of d_out)
  gemm_bt<32, false><<<MT * 2, 256, 0, stream>>>(hbuf, wf2, 1024, 2, 256,
                                                 b_ffn2, 1.f, bshb, 1.f,
                                                 nullptr, out, NQ);
}